// Round 1
// baseline (418.346 us; speedup 1.0000x reference)
//
#include <hip/hip_runtime.h>
#include <hip/hip_bf16.h>

typedef __hip_bfloat16 bf16;
typedef short bf16x8 __attribute__((ext_vector_type(8)));
typedef float f32x4 __attribute__((ext_vector_type(4)));

// B=4, T=2048, D=1024, H=16, HD=64

static __device__ __forceinline__ void glds16(const bf16* g, bf16* l) {
  __builtin_amdgcn_global_load_lds(
      (const __attribute__((address_space(1))) void*)g,
      (__attribute__((address_space(3))) void*)l, 16, 0, 0);
}

static __device__ __forceinline__ unsigned short f2b(float f) {
  return __builtin_bit_cast(unsigned short, __float2bfloat16(f));
}

// ---------------- fp32 -> bf16 convert, 4 elems/thread ----------------
__global__ void k_convert(const float* __restrict__ in, unsigned short* __restrict__ out, int n4) {
  int i = blockIdx.x * 256 + threadIdx.x;
  if (i >= n4) return;
  float4 v = reinterpret_cast<const float4*>(in)[i];
  ushort4 o;
  o.x = f2b(v.x); o.y = f2b(v.y); o.z = f2b(v.z); o.w = f2b(v.w);
  reinterpret_cast<ushort4*>(out)[i] = o;
}

// ---------------- transpose R x C fp32  ->  C x R bf16 ----------------
__global__ void k_transpose(const float* __restrict__ in, bf16* __restrict__ out, int R, int C) {
  __shared__ float t[32][33];
  int c0 = blockIdx.x * 32, r0 = blockIdx.y * 32;
  int tx = threadIdx.x, ty = threadIdx.y;  // block (32,8)
  #pragma unroll
  for (int j = 0; j < 32; j += 8)
    t[ty + j][tx] = in[(size_t)(r0 + ty + j) * C + c0 + tx];
  __syncthreads();
  #pragma unroll
  for (int j = 0; j < 32; j += 8)
    out[(size_t)(c0 + ty + j) * R + r0 + tx] = __float2bfloat16(t[tx][ty + j]);
}

// ---------------- GEMM: C = A(M x 1024) * Bt(N x 1024)^T + bias ----------------
// EPI 0: scatter to Qh/Kh[b][h][t][d], Vt[b][h][d][t] (bf16, +b_qkv)
// EPI 1: Out fp32 [m][1024] (+b_fc)
template<int EPI>
__global__ __launch_bounds__(256, 2)
void k_gemm(const bf16* __restrict__ A, const bf16* __restrict__ Bt,
            const float* __restrict__ bias,
            bf16* __restrict__ Qh, bf16* __restrict__ Kh, bf16* __restrict__ Vt,
            float* __restrict__ Out)
{
  constexpr int K = 1024;
  __shared__ bf16 sA[128 * 32];
  __shared__ bf16 sB[128 * 32];
  const int tid = threadIdx.x;
  const int wv = tid >> 6, lane = tid & 63;
  const int wr = wv >> 1, wc = wv & 1;
  const int l4 = lane >> 4, l15 = lane & 15;
  const int bx = blockIdx.x, by = blockIdx.y;

  const int srow = lane >> 2;         // 0..15
  const int scol = (lane & 3) * 8;    // element offset 0,8,16,24
  const bf16* gA0 = A  + (size_t)(by * 128 + wv * 16 + srow) * K + scol;
  const bf16* gB0 = Bt + (size_t)(bx * 128 + wv * 16 + srow) * K + scol;
  bf16* lA0 = sA + wv * 16 * 32;      // wave-uniform LDS base; HW adds lane*16B
  bf16* lB0 = sB + wv * 16 * 32;

  f32x4 acc[4][4];
  #pragma unroll
  for (int i = 0; i < 4; ++i)
    #pragma unroll
    for (int j = 0; j < 4; ++j) acc[i][j] = f32x4{0.f, 0.f, 0.f, 0.f};

  for (int kb = 0; kb < K; kb += 32) {
    glds16(gA0 + kb,                   lA0);
    glds16(gA0 + kb + (size_t)64 * K,  lA0 + 64 * 32);
    glds16(gB0 + kb,                   lB0);
    glds16(gB0 + kb + (size_t)64 * K,  lB0 + 64 * 32);
    __syncthreads();
    bf16x8 af[4], bfr[4];
    #pragma unroll
    for (int i = 0; i < 4; ++i)
      af[i] = *reinterpret_cast<const bf16x8*>(sA + (wr * 64 + i * 16 + l15) * 32 + l4 * 8);
    #pragma unroll
    for (int j = 0; j < 4; ++j)
      bfr[j] = *reinterpret_cast<const bf16x8*>(sB + (wc * 64 + j * 16 + l15) * 32 + l4 * 8);
    #pragma unroll
    for (int i = 0; i < 4; ++i)
      #pragma unroll
      for (int j = 0; j < 4; ++j)
        acc[i][j] = __builtin_amdgcn_mfma_f32_16x16x32_bf16(af[i], bfr[j], acc[i][j], 0, 0, 0);
    __syncthreads();
  }

  if (EPI == 0) {
    #pragma unroll
    for (int j = 0; j < 4; ++j) {
      const int n = bx * 128 + wc * 64 + j * 16 + l15;
      const float bj = bias[n];
      const int s = n >> 10;
      const int hh = (n >> 6) & 15;
      const int d = n & 63;
      #pragma unroll
      for (int i = 0; i < 4; ++i) {
        #pragma unroll
        for (int r = 0; r < 4; ++r) {
          const int m = by * 128 + wr * 64 + i * 16 + l4 * 4 + r;
          const int bb = m >> 11, t = m & 2047;
          const bf16 o = __float2bfloat16(acc[i][j][r] + bj);
          if (s == 0)      Qh[((size_t)((bb * 16 + hh) * 2048 + t)) * 64 + d] = o;
          else if (s == 1) Kh[((size_t)((bb * 16 + hh) * 2048 + t)) * 64 + d] = o;
          else             Vt[((size_t)((bb * 16 + hh) * 64 + d)) * 2048 + t] = o;
        }
      }
    }
  } else {
    #pragma unroll
    for (int j = 0; j < 4; ++j) {
      const int n = bx * 128 + wc * 64 + j * 16 + l15;
      const float bj = bias[n];
      #pragma unroll
      for (int i = 0; i < 4; ++i)
        #pragma unroll
        for (int r = 0; r < 4; ++r) {
          const int m = by * 128 + wr * 64 + i * 16 + l4 * 4 + r;
          Out[(size_t)m * 1024 + n] = acc[i][j][r] + bj;
        }
    }
  }
}

// ---------------- flash attention (causal), head-major inputs ----------------
// grid (T/128, H, B), block 256 = 4 independent waves, 32 q-rows/wave, KT=64
__global__ __launch_bounds__(256, 2)
void k_attn(const bf16* __restrict__ Qh, const bf16* __restrict__ Kh,
            const bf16* __restrict__ Vt, bf16* __restrict__ Ao)
{
  __shared__ bf16 Pl[4][32 * 72];   // per-wave P tile, stride 72 (bank-friendly)
  const int tid = threadIdx.x;
  const int wv = tid >> 6, lane = tid & 63;
  const int l4 = lane >> 4, l15 = lane & 15;
  const int qt = blockIdx.x, h = blockIdx.y, b = blockIdx.z;
  const bf16* Qp = Qh + (size_t)(b * 16 + h) * 2048 * 64;
  const bf16* Kp = Kh + (size_t)(b * 16 + h) * 2048 * 64;
  const bf16* Vp = Vt + (size_t)(b * 16 + h) * 64 * 2048;
  const int qbase = qt * 128 + wv * 32;
  bf16* Pw = &Pl[wv][0];

  bf16x8 qa[2][2];
  #pragma unroll
  for (int i = 0; i < 2; ++i)
    #pragma unroll
    for (int kh = 0; kh < 2; ++kh)
      qa[i][kh] = *reinterpret_cast<const bf16x8*>(
          Qp + (size_t)(qbase + i * 16 + l15) * 64 + kh * 32 + l4 * 8);

  f32x4 o[2][4];
  float mr[2][4], lr[2][4];
  #pragma unroll
  for (int i = 0; i < 2; ++i) {
    #pragma unroll
    for (int jd = 0; jd < 4; ++jd) o[i][jd] = f32x4{0.f, 0.f, 0.f, 0.f};
    #pragma unroll
    for (int r = 0; r < 4; ++r) { mr[i][r] = -1e30f; lr[i][r] = 0.f; }
  }

  const int ktmax = (qbase + 31) >> 6;
  for (int kt = 0; kt <= ktmax; ++kt) {
    const bool full = (kt * 64 + 63) <= qbase;
    bf16x8 kbf[4][2];
    #pragma unroll
    for (int j = 0; j < 4; ++j)
      #pragma unroll
      for (int kh = 0; kh < 2; ++kh)
        kbf[j][kh] = *reinterpret_cast<const bf16x8*>(
            Kp + (size_t)(kt * 64 + j * 16 + l15) * 64 + kh * 32 + l4 * 8);
    f32x4 s[2][4];
    #pragma unroll
    for (int i = 0; i < 2; ++i)
      #pragma unroll
      for (int j = 0; j < 4; ++j) s[i][j] = f32x4{0.f, 0.f, 0.f, 0.f};
    #pragma unroll
    for (int i = 0; i < 2; ++i)
      #pragma unroll
      for (int j = 0; j < 4; ++j)
        #pragma unroll
        for (int kh = 0; kh < 2; ++kh)
          s[i][j] = __builtin_amdgcn_mfma_f32_16x16x32_bf16(qa[i][kh], kbf[j][kh], s[i][j], 0, 0, 0);

    // scale + causal mask (C-layout: row=(lane>>4)*4+r, col=lane&15)
    #pragma unroll
    for (int i = 0; i < 2; ++i)
      #pragma unroll
      for (int j = 0; j < 4; ++j)
        #pragma unroll
        for (int r = 0; r < 4; ++r) {
          float v = s[i][j][r] * 0.125f;
          if (!full) {
            const int q = qbase + i * 16 + l4 * 4 + r;
            const int kk = kt * 64 + j * 16 + l15;
            if (kk > q) v = -1e30f;
          }
          s[i][j][r] = v;
        }

    // online softmax per row (rows live in 16-lane groups)
    #pragma unroll
    for (int i = 0; i < 2; ++i)
      #pragma unroll
      for (int r = 0; r < 4; ++r) {
        float mx = fmaxf(fmaxf(s[i][0][r], s[i][1][r]), fmaxf(s[i][2][r], s[i][3][r]));
        #pragma unroll
        for (int dd = 1; dd < 16; dd <<= 1) mx = fmaxf(mx, __shfl_xor(mx, dd, 16));
        const float mn = fmaxf(mr[i][r], mx);
        const float al = __expf(mr[i][r] - mn);
        mr[i][r] = mn;
        float ps = 0.f;
        #pragma unroll
        for (int j = 0; j < 4; ++j) {
          const float p = __expf(s[i][j][r] - mn);
          ps += p;
          Pw[(i * 16 + l4 * 4 + r) * 72 + j * 16 + l15] = __float2bfloat16(p);
        }
        #pragma unroll
        for (int dd = 1; dd < 16; dd <<= 1) ps += __shfl_xor(ps, dd, 16);
        lr[i][r] = lr[i][r] * al + ps;
        #pragma unroll
        for (int jd = 0; jd < 4; ++jd) o[i][jd][r] *= al;
      }

    // PV: A-frags from P LDS, B-frags from transposed V (contiguous 16B)
    bf16x8 vbf[4][2];
    #pragma unroll
    for (int jd = 0; jd < 4; ++jd)
      #pragma unroll
      for (int kh = 0; kh < 2; ++kh)
        vbf[jd][kh] = *reinterpret_cast<const bf16x8*>(
            Vp + (size_t)(jd * 16 + l15) * 2048 + kt * 64 + kh * 32 + l4 * 8);
    bf16x8 pa[2][2];
    #pragma unroll
    for (int i = 0; i < 2; ++i)
      #pragma unroll
      for (int kh = 0; kh < 2; ++kh)
        pa[i][kh] = *reinterpret_cast<const bf16x8*>(Pw + (i * 16 + l15) * 72 + kh * 32 + l4 * 8);
    #pragma unroll
    for (int i = 0; i < 2; ++i)
      #pragma unroll
      for (int jd = 0; jd < 4; ++jd)
        #pragma unroll
        for (int kh = 0; kh < 2; ++kh)
          o[i][jd] = __builtin_amdgcn_mfma_f32_16x16x32_bf16(pa[i][kh], vbf[jd][kh], o[i][jd], 0, 0, 0);
  }

  #pragma unroll
  for (int i = 0; i < 2; ++i)
    #pragma unroll
    for (int r = 0; r < 4; ++r) {
      const float inv = 1.f / lr[i][r];
      const int q = qbase + i * 16 + l4 * 4 + r;
      #pragma unroll
      for (int jd = 0; jd < 4; ++jd) {
        const int d = jd * 16 + l15;
        Ao[(size_t)(b * 2048 + q) * 1024 + h * 64 + d] = __float2bfloat16(o[i][jd][r] * inv);
      }
    }
}

extern "C" void kernel_launch(void* const* d_in, const int* in_sizes, int n_in,
                              void* d_out, int out_size, void* d_ws, size_t ws_size,
                              hipStream_t stream)
{
  const float* x     = (const float*)d_in[0];
  const float* W_qkv = (const float*)d_in[1];
  const float* b_qkv = (const float*)d_in[2];
  const float* W_fc  = (const float*)d_in[3];
  const float* b_fc  = (const float*)d_in[4];
  float* out = (float*)d_out;

  char* ws = (char*)d_ws;
  bf16* x_bf = (bf16*)ws;  ws += (size_t)8192 * 1024 * 2;            // 16 MB
  bf16* Wqt  = (bf16*)ws;  ws += (size_t)3072 * 1024 * 2;            //  6 MB
  bf16* Wft  = (bf16*)ws;  ws += (size_t)1024 * 1024 * 2;            //  2 MB
  bf16* Qh   = (bf16*)ws;  ws += (size_t)4 * 16 * 2048 * 64 * 2;     // 16 MB
  bf16* Kh   = (bf16*)ws;  ws += (size_t)4 * 16 * 2048 * 64 * 2;     // 16 MB
  bf16* Vt   = (bf16*)ws;  ws += (size_t)4 * 16 * 64 * 2048 * 2;     // 16 MB
  bf16* Ao   = (bf16*)ws;  ws += (size_t)8192 * 1024 * 2;            // 16 MB  (total 88 MB)

  k_convert<<<8192, 256, 0, stream>>>(x, (unsigned short*)x_bf, 8192 * 1024 / 4);
  k_transpose<<<dim3(3072 / 32, 1024 / 32), dim3(32, 8), 0, stream>>>(W_qkv, Wqt, 1024, 3072);
  k_transpose<<<dim3(1024 / 32, 1024 / 32), dim3(32, 8), 0, stream>>>(W_fc, Wft, 1024, 1024);
  k_gemm<0><<<dim3(24, 64), 256, 0, stream>>>(x_bf, Wqt, b_qkv, Qh, Kh, Vt, nullptr);
  k_attn<<<dim3(16, 16, 4), 256, 0, stream>>>(Qh, Kh, Vt, Ao);
  k_gemm<1><<<dim3(8, 64), 256, 0, stream>>>(Ao, Wft, b_fc, nullptr, nullptr, nullptr, out);
}

// Round 2
// 380.707 us; speedup vs baseline: 1.0989x; 1.0989x over previous
//
#include <hip/hip_runtime.h>
#include <hip/hip_bf16.h>

typedef __hip_bfloat16 bf16;
typedef short bf16x8 __attribute__((ext_vector_type(8)));
typedef float f32x4 __attribute__((ext_vector_type(4)));

// B=4, T=2048, D=1024, H=16, HD=64

static __device__ __forceinline__ void glds16(const bf16* g, bf16* l) {
  __builtin_amdgcn_global_load_lds(
      (const __attribute__((address_space(1))) void*)g,
      (__attribute__((address_space(3))) void*)l, 16, 0, 0);
}

static __device__ __forceinline__ unsigned short f2b(float f) {
  return __builtin_bit_cast(unsigned short, __float2bfloat16(f));
}

// ---------------- fp32 -> bf16 convert, 4 elems/thread ----------------
__global__ void k_convert(const float* __restrict__ in, unsigned short* __restrict__ out, int n4) {
  int i = blockIdx.x * 256 + threadIdx.x;
  if (i >= n4) return;
  float4 v = reinterpret_cast<const float4*>(in)[i];
  ushort4 o;
  o.x = f2b(v.x); o.y = f2b(v.y); o.z = f2b(v.z); o.w = f2b(v.w);
  reinterpret_cast<ushort4*>(out)[i] = o;
}

// ---------------- transpose R x C fp32  ->  C x R bf16 ----------------
__global__ void k_transpose(const float* __restrict__ in, bf16* __restrict__ out, int R, int C) {
  __shared__ float t[32][33];
  int c0 = blockIdx.x * 32, r0 = blockIdx.y * 32;
  int tx = threadIdx.x, ty = threadIdx.y;  // block (32,8)
  #pragma unroll
  for (int j = 0; j < 32; j += 8)
    t[ty + j][tx] = in[(size_t)(r0 + ty + j) * C + c0 + tx];
  __syncthreads();
  #pragma unroll
  for (int j = 0; j < 32; j += 8)
    out[(size_t)(c0 + ty + j) * R + r0 + tx] = __float2bfloat16(t[tx][ty + j]);
}

// ---------------- GEMM: C = A(M x 1024) * Bt(N x 1024)^T + bias ----------------
// EPI 0: scatter to Qh/Kh[b][h][t][d], Vt[b][h][d][t] (bf16, +b_qkv)
// EPI 1: Out fp32 [m][1024] (+b_fc)
template<int EPI>
__global__ __launch_bounds__(256, 2)
void k_gemm(const bf16* __restrict__ A, const bf16* __restrict__ Bt,
            const float* __restrict__ bias,
            bf16* __restrict__ Qh, bf16* __restrict__ Kh, bf16* __restrict__ Vt,
            float* __restrict__ Out)
{
  constexpr int K = 1024;
  __shared__ bf16 sA[128 * 32];
  __shared__ bf16 sB[128 * 32];
  const int tid = threadIdx.x;
  const int wv = tid >> 6, lane = tid & 63;
  const int wr = wv >> 1, wc = wv & 1;
  const int l4 = lane >> 4, l15 = lane & 15;

  // XCD-aware bijective swizzle (nwg % 8 == 0 for both grids: 1536, 512)
  const int nbx = gridDim.x;
  const int nwg = nbx * gridDim.y;
  const int flat = blockIdx.y * nbx + blockIdx.x;
  const int cpx = nwg >> 3;
  const int swz = (flat & 7) * cpx + (flat >> 3);
  const int bx = swz % nbx;
  const int by = swz / nbx;

  const int srow = lane >> 2;         // 0..15
  const int scol = (lane & 3) * 8;    // element offset 0,8,16,24
  const bf16* gA0 = A  + (size_t)(by * 128 + wv * 16 + srow) * K + scol;
  const bf16* gB0 = Bt + (size_t)(bx * 128 + wv * 16 + srow) * K + scol;
  bf16* lA0 = sA + wv * 16 * 32;      // wave-uniform LDS base; HW adds lane*16B
  bf16* lB0 = sB + wv * 16 * 32;

  f32x4 acc[4][4];
  #pragma unroll
  for (int i = 0; i < 4; ++i)
    #pragma unroll
    for (int j = 0; j < 4; ++j) acc[i][j] = f32x4{0.f, 0.f, 0.f, 0.f};

  for (int kb = 0; kb < K; kb += 32) {
    glds16(gA0 + kb,                   lA0);
    glds16(gA0 + kb + (size_t)64 * K,  lA0 + 64 * 32);
    glds16(gB0 + kb,                   lB0);
    glds16(gB0 + kb + (size_t)64 * K,  lB0 + 64 * 32);
    __syncthreads();
    bf16x8 af[4], bfr[4];
    #pragma unroll
    for (int i = 0; i < 4; ++i)
      af[i] = *reinterpret_cast<const bf16x8*>(sA + (wr * 64 + i * 16 + l15) * 32 + l4 * 8);
    #pragma unroll
    for (int j = 0; j < 4; ++j)
      bfr[j] = *reinterpret_cast<const bf16x8*>(sB + (wc * 64 + j * 16 + l15) * 32 + l4 * 8);
    #pragma unroll
    for (int i = 0; i < 4; ++i)
      #pragma unroll
      for (int j = 0; j < 4; ++j)
        acc[i][j] = __builtin_amdgcn_mfma_f32_16x16x32_bf16(af[i], bfr[j], acc[i][j], 0, 0, 0);
    __syncthreads();
  }

  if (EPI == 0) {
    #pragma unroll
    for (int j = 0; j < 4; ++j) {
      const int n = bx * 128 + wc * 64 + j * 16 + l15;
      const float bj = bias[n];
      const int s = n >> 10;
      const int hh = (n >> 6) & 15;
      const int d = n & 63;
      #pragma unroll
      for (int i = 0; i < 4; ++i) {
        #pragma unroll
        for (int r = 0; r < 4; ++r) {
          const int m = by * 128 + wr * 64 + i * 16 + l4 * 4 + r;
          const int bb = m >> 11, t = m & 2047;
          const bf16 o = __float2bfloat16(acc[i][j][r] + bj);
          if (s == 0)      Qh[((size_t)((bb * 16 + hh) * 2048 + t)) * 64 + d] = o;
          else if (s == 1) Kh[((size_t)((bb * 16 + hh) * 2048 + t)) * 64 + d] = o;
          else             Vt[((size_t)((bb * 16 + hh) * 64 + d)) * 2048 + t] = o;
        }
      }
    }
  } else {
    #pragma unroll
    for (int j = 0; j < 4; ++j) {
      const int n = bx * 128 + wc * 64 + j * 16 + l15;
      const float bj = bias[n];
      #pragma unroll
      for (int i = 0; i < 4; ++i)
        #pragma unroll
        for (int r = 0; r < 4; ++r) {
          const int m = by * 128 + wr * 64 + i * 16 + l4 * 4 + r;
          Out[(size_t)m * 1024 + n] = acc[i][j][r] + bj;
        }
    }
  }
}

// ---------------- flash attention (causal), head-major inputs ----------------
// grid (16, H, B), block 256 = 4 independent waves.
// Causal fold: block g's 4 waves take q-tiles {g, 31-g, 32+g, 63-g} (32 rows
// each) -> every block has identical total cost (~67 kt-iters). Role rotated
// by (wv+b)&3 so SIMDs also mix roles.
__global__ __launch_bounds__(256, 4)
void k_attn(const bf16* __restrict__ Qh, const bf16* __restrict__ Kh,
            const bf16* __restrict__ Vt, bf16* __restrict__ Ao)
{
  __shared__ bf16 Pl[4][32 * 72];   // per-wave P tile, stride 72 (bank-friendly)
  const int tid = threadIdx.x;
  const int wv = tid >> 6, lane = tid & 63;
  const int l4 = lane >> 4, l15 = lane & 15;
  const int g = blockIdx.x, h = blockIdx.y, b = blockIdx.z;
  const int role = (wv + b) & 3;
  const int qi = (role == 0) ? g : (role == 1) ? (31 - g) : (role == 2) ? (32 + g) : (63 - g);
  const int qbase = qi * 32;

  const bf16* Qp = Qh + (size_t)(b * 16 + h) * 2048 * 64;
  const bf16* Kp = Kh + (size_t)(b * 16 + h) * 2048 * 64;
  const bf16* Vp = Vt + (size_t)(b * 16 + h) * 64 * 2048;
  bf16* Pw = &Pl[wv][0];

  bf16x8 qa[2][2];
  #pragma unroll
  for (int i = 0; i < 2; ++i)
    #pragma unroll
    for (int kh = 0; kh < 2; ++kh)
      qa[i][kh] = *reinterpret_cast<const bf16x8*>(
          Qp + (size_t)(qbase + i * 16 + l15) * 64 + kh * 32 + l4 * 8);

  f32x4 o[2][4];
  float mr[2][4], lr[2][4];
  #pragma unroll
  for (int i = 0; i < 2; ++i) {
    #pragma unroll
    for (int jd = 0; jd < 4; ++jd) o[i][jd] = f32x4{0.f, 0.f, 0.f, 0.f};
    #pragma unroll
    for (int r = 0; r < 4; ++r) { mr[i][r] = -1e30f; lr[i][r] = 0.f; }
  }

  const int ktmax = (qbase + 31) >> 6;
  for (int kt = 0; kt <= ktmax; ++kt) {
    const bool full = (kt * 64 + 63) <= qbase;
    bf16x8 kbf[4][2];
    #pragma unroll
    for (int j = 0; j < 4; ++j)
      #pragma unroll
      for (int kh = 0; kh < 2; ++kh)
        kbf[j][kh] = *reinterpret_cast<const bf16x8*>(
            Kp + (size_t)(kt * 64 + j * 16 + l15) * 64 + kh * 32 + l4 * 8);
    f32x4 s[2][4];
    #pragma unroll
    for (int i = 0; i < 2; ++i)
      #pragma unroll
      for (int j = 0; j < 4; ++j) s[i][j] = f32x4{0.f, 0.f, 0.f, 0.f};
    #pragma unroll
    for (int i = 0; i < 2; ++i)
      #pragma unroll
      for (int j = 0; j < 4; ++j)
        #pragma unroll
        for (int kh = 0; kh < 2; ++kh)
          s[i][j] = __builtin_amdgcn_mfma_f32_16x16x32_bf16(qa[i][kh], kbf[j][kh], s[i][j], 0, 0, 0);

    // scale + causal mask (C-layout: row=(lane>>4)*4+r, col=lane&15)
    #pragma unroll
    for (int i = 0; i < 2; ++i)
      #pragma unroll
      for (int j = 0; j < 4; ++j)
        #pragma unroll
        for (int r = 0; r < 4; ++r) {
          float v = s[i][j][r] * 0.125f;
          if (!full) {
            const int q = qbase + i * 16 + l4 * 4 + r;
            const int kk = kt * 64 + j * 16 + l15;
            if (kk > q) v = -1e30f;
          }
          s[i][j][r] = v;
        }

    // V loads issued early: latency hides under softmax VALU
    bf16x8 vbf[4][2];
    #pragma unroll
    for (int jd = 0; jd < 4; ++jd)
      #pragma unroll
      for (int kh = 0; kh < 2; ++kh)
        vbf[jd][kh] = *reinterpret_cast<const bf16x8*>(
            Vp + (size_t)(jd * 16 + l15) * 2048 + kt * 64 + kh * 32 + l4 * 8);

    // online softmax per row (rows live in 16-lane groups)
    #pragma unroll
    for (int i = 0; i < 2; ++i)
      #pragma unroll
      for (int r = 0; r < 4; ++r) {
        float mx = fmaxf(fmaxf(s[i][0][r], s[i][1][r]), fmaxf(s[i][2][r], s[i][3][r]));
        #pragma unroll
        for (int dd = 1; dd < 16; dd <<= 1) mx = fmaxf(mx, __shfl_xor(mx, dd, 16));
        const float mn = fmaxf(mr[i][r], mx);
        const float al = __expf(mr[i][r] - mn);
        mr[i][r] = mn;
        float ps = 0.f;
        #pragma unroll
        for (int j = 0; j < 4; ++j) {
          const float p = __expf(s[i][j][r] - mn);
          ps += p;
          Pw[(i * 16 + l4 * 4 + r) * 72 + j * 16 + l15] = __float2bfloat16(p);
        }
        #pragma unroll
        for (int dd = 1; dd < 16; dd <<= 1) ps += __shfl_xor(ps, dd, 16);
        lr[i][r] = lr[i][r] * al + ps;
        #pragma unroll
        for (int jd = 0; jd < 4; ++jd) o[i][jd][r] *= al;
      }

    // PV: A-frags from P LDS, B-frags from transposed V (contiguous 16B)
    bf16x8 pa[2][2];
    #pragma unroll
    for (int i = 0; i < 2; ++i)
      #pragma unroll
      for (int kh = 0; kh < 2; ++kh)
        pa[i][kh] = *reinterpret_cast<const bf16x8*>(Pw + (i * 16 + l15) * 72 + kh * 32 + l4 * 8);
    #pragma unroll
    for (int i = 0; i < 2; ++i)
      #pragma unroll
      for (int jd = 0; jd < 4; ++jd)
        #pragma unroll
        for (int kh = 0; kh < 2; ++kh)
          o[i][jd] = __builtin_amdgcn_mfma_f32_16x16x32_bf16(pa[i][kh], vbf[jd][kh], o[i][jd], 0, 0, 0);
  }

  #pragma unroll
  for (int i = 0; i < 2; ++i)
    #pragma unroll
    for (int r = 0; r < 4; ++r) {
      const float inv = 1.f / lr[i][r];
      const int q = qbase + i * 16 + l4 * 4 + r;
      #pragma unroll
      for (int jd = 0; jd < 4; ++jd) {
        const int d = jd * 16 + l15;
        Ao[(size_t)(b * 2048 + q) * 1024 + h * 64 + d] = __float2bfloat16(o[i][jd][r] * inv);
      }
    }
}

extern "C" void kernel_launch(void* const* d_in, const int* in_sizes, int n_in,
                              void* d_out, int out_size, void* d_ws, size_t ws_size,
                              hipStream_t stream)
{
  const float* x     = (const float*)d_in[0];
  const float* W_qkv = (const float*)d_in[1];
  const float* b_qkv = (const float*)d_in[2];
  const float* W_fc  = (const float*)d_in[3];
  const float* b_fc  = (const float*)d_in[4];
  float* out = (float*)d_out;

  char* ws = (char*)d_ws;
  bf16* x_bf = (bf16*)ws;  ws += (size_t)8192 * 1024 * 2;            // 16 MB
  bf16* Wqt  = (bf16*)ws;  ws += (size_t)3072 * 1024 * 2;            //  6 MB
  bf16* Wft  = (bf16*)ws;  ws += (size_t)1024 * 1024 * 2;            //  2 MB
  bf16* Qh   = (bf16*)ws;  ws += (size_t)4 * 16 * 2048 * 64 * 2;     // 16 MB
  bf16* Kh   = (bf16*)ws;  ws += (size_t)4 * 16 * 2048 * 64 * 2;     // 16 MB
  bf16* Vt   = (bf16*)ws;  ws += (size_t)4 * 16 * 64 * 2048 * 2;     // 16 MB
  bf16* Ao   = (bf16*)ws;  ws += (size_t)8192 * 1024 * 2;            // 16 MB  (total 88 MB)

  k_convert<<<8192, 256, 0, stream>>>(x, (unsigned short*)x_bf, 8192 * 1024 / 4);
  k_transpose<<<dim3(3072 / 32, 1024 / 32), dim3(32, 8), 0, stream>>>(W_qkv, Wqt, 1024, 3072);
  k_transpose<<<dim3(1024 / 32, 1024 / 32), dim3(32, 8), 0, stream>>>(W_fc, Wft, 1024, 1024);
  k_gemm<0><<<dim3(24, 64), 256, 0, stream>>>(x_bf, Wqt, b_qkv, Qh, Kh, Vt, nullptr);
  k_attn<<<dim3(16, 16, 4), 256, 0, stream>>>(Qh, Kh, Vt, Ao);
  k_gemm<1><<<dim3(8, 64), 256, 0, stream>>>(Ao, Wft, b_fc, nullptr, nullptr, nullptr, out);
}